// Round 26
// baseline (185.594 us; speedup 1.0000x reference)
//
#include <hip/hip_runtime.h>

#define BATCH 4096
#define DDIM  512
#define FEWN  128
#define LDA1  640     // A1 = [hr'(512) | attn(128)]
#define GATEN 2048    // live permuted gate cols (j<512 only; j>=512 half is dead code)
#define CDIM  512     // live c-state width

typedef unsigned short ushort_t;
typedef __attribute__((ext_vector_type(8))) short bf16x8;
typedef __attribute__((ext_vector_type(4))) float f32x4;

__device__ inline ushort_t f2bf(float f) {
  unsigned u = __float_as_uint(f);
  unsigned r = (u + 0x7FFFu + ((u >> 16) & 1u)) >> 16;
  return (ushort_t)r;
}
__device__ inline float bf2f(ushort_t h) { return __uint_as_float((unsigned)h << 16); }
__device__ inline float bf2f_u(unsigned h16) { return __uint_as_float(h16 << 16); }

__device__ inline float sigmoidf(float x) { return 1.f / (1.f + __expf(-x)); }
__device__ inline float tanh_fast(float x) {
  float ax = fabsf(x);
  float t = __expf(-2.f * ax);
  float r = (1.f - t) / (1.f + t);
  return copysignf(r, x);
}

// permuted layout over LIVE cols colp<2048: j = (colp>>6)*16 + (colp&15), gate = (colp>>4)&3
__device__ inline int orig_row(int colp) {
  return ((colp >> 4) & 3) * 1024 + ((colp >> 6) << 4) + (colp & 15);
}

__device__ inline void async_copy16(ushort_t* lds, const ushort_t* g) {
  __builtin_amdgcn_global_load_lds(
      (const __attribute__((address_space(1))) unsigned int*)g,
      (__attribute__((address_space(3))) unsigned int*)lds, 16, 0, 0);
}

// XCD-aware block map (column-slice when gx%8==0, else bijective 1D)
__device__ inline void xcd_map(int gx, int gy, int id, int& bx, int& by) {
  if ((gx & 7) == 0) {
    const int cpx = gx >> 3;
    const int x = id & 7, s = id >> 3;
    bx = x * cpx + (s % cpx);
    by = s / cpx;
  } else {
    const int nwg = gx * gy;
    const int qq = nwg >> 3, rr = nwg & 7;
    const int x = id & 7, s = id >> 3;
    const int nid = (x < rr ? x * (qq + 1) : rr * (qq + 1) + (x - rr) * qq) + s;
    bx = nid % gx; by = nid / gx;
  }
}

// ---- K-loop: BK=64, double-buffered, counted vmcnt (no vmcnt(0) mid-loop).
#define STAGE8(dA, dB, kk)                                                   \
    async_copy16(dA,              gA0 + (kk));                               \
    async_copy16(dA + 512,        gA0 + (size_t)16 * lda + (kk));            \
    async_copy16(dA + 4096,       gA0 + (kk) + 32);                          \
    async_copy16(dA + 4096 + 512, gA0 + (size_t)16 * lda + (kk) + 32);       \
    async_copy16(dB,              gB0 + (kk));                               \
    async_copy16(dB + 512,        gB0 + (size_t)16 * ldb + (kk));            \
    async_copy16(dB + 4096,       gB0 + (kk) + 32);                          \
    async_copy16(dB + 4096 + 512, gB0 + (size_t)16 * ldb + (kk) + 32);

#define KLOOP_DBUF()                                                         \
  const int nIter = K >> 6;                                                  \
  { STAGE8(sA, sB, 0) }                                                      \
  if (nIter > 1) { STAGE8(sA + 8192, sB + 8192, 64) }                        \
  for (int kt = 0; kt < nIter; ++kt) {                                       \
    if (kt + 1 < nIter) asm volatile("s_waitcnt vmcnt(8)" ::: "memory");     \
    else                asm volatile("s_waitcnt vmcnt(0)" ::: "memory");     \
    __builtin_amdgcn_s_barrier();                                            \
    const int cur = (kt & 1) * 8192;                                         \
    _Pragma("unroll")                                                        \
    for (int h = 0; h < 2; ++h) {                                            \
      bf16x8 af[4], bfr[4];                                                  \
      _Pragma("unroll")                                                      \
      for (int mi = 0; mi < 4; ++mi)                                         \
        af[mi] = *(const bf16x8*)&lA[cur + h * 4096 + (wr * 64 + mi * 16 + lr) * 32 + kg * 8]; \
      _Pragma("unroll")                                                      \
      for (int ni = 0; ni < 4; ++ni)                                         \
        bfr[ni] = *(const bf16x8*)&lB[cur + h * 4096 + (wc * 64 + ni * 16 + lr) * 32 + kg * 8]; \
      _Pragma("unroll")                                                      \
      for (int mi = 0; mi < 4; ++mi)                                         \
        _Pragma("unroll")                                                    \
        for (int ni = 0; ni < 4; ++ni)                                       \
          acc[mi][ni] = __builtin_amdgcn_mfma_f32_16x16x32_bf16(af[mi], bfr[ni], acc[mi][ni], 0, 0, 0); \
    }                                                                        \
    __builtin_amdgcn_s_barrier();                                            \
    if (kt + 2 < nIter) {                                                    \
      const int k2 = (kt + 2) << 6;                                          \
      STAGE8(sA + cur, sB + cur, k2)                                         \
    }                                                                        \
  }

// common per-thread ids + LDS decl
#define TILE_COMMON()                                                        \
  __shared__ __align__(16) ushort_t lA[2 * 8192];                            \
  __shared__ __align__(16) ushort_t lB[2 * 8192];                            \
  const int tid = threadIdx.x;                                               \
  const int wid = tid >> 6, lane = tid & 63;                                 \
  const int wr = wid >> 1, wc = wid & 1;                                     \
  const int lr = lane & 15, kg = lane >> 4;                                  \
  const int srow = lane >> 2;                                                \
  const int scol = (lane & 3) * 8;                                           \
  f32x4 acc[4][4] = {};                                                      \
  ushort_t* sA = &lA[wid * 1024];                                            \
  ushort_t* sB = &lB[wid * 1024];

// Fused recurrent GEMM + LSTM cell, BM=64 (grid (16,64) = 1024 blocks = 4/CU).
// Waves 2x2: each 32 rows (mi<2) x 64 cols (ni<4 = all 4 gates of j). BK=32 dbuf,
// 3 gload_lds/wave/iter, counted vmcnt(3). K-order identical to BK=64 version ->
// bitwise-identical accumulation. MODE 1: cell -> c, A1.hi, A2.lo. MODE 2: out.
template<int MODE>
__launch_bounds__(256)
__global__ void gemm_fused64(const ushort_t* __restrict__ A, const ushort_t* __restrict__ B,
                             const ushort_t* __restrict__ base, ushort_t* __restrict__ c,
                             ushort_t* __restrict__ A1out, ushort_t* __restrict__ A2out,
                             const float* __restrict__ query, float* __restrict__ out,
                             int K, int lda, int ldb) {
  __shared__ __align__(16) ushort_t lA[2 * 2048];   // [2][64][32]
  __shared__ __align__(16) ushort_t lB[2 * 4096];   // [2][128][32]
  const int tid = threadIdx.x;
  const int wid = tid >> 6, lane = tid & 63;
  const int wr = wid >> 1, wc = wid & 1;
  const int lr = lane & 15, kg = lane >> 4;
  const int srow = lane >> 2;
  const int scol = (lane & 3) * 8;
  f32x4 acc[2][4] = {};
  int bx, by;
  xcd_map(gridDim.x, gridDim.y, blockIdx.y * gridDim.x + blockIdx.x, bx, by);
  const int m0 = by * 64, n0 = bx * 128;
  const ushort_t* gA0 = A + (size_t)(m0 + wid * 16 + srow) * lda + scol;   // wave stages 16 A-rows
  const ushort_t* gB0 = B + (size_t)(n0 + wid * 32 + srow) * ldb + scol;   // wave stages 32 B-rows
  ushort_t* sA = &lA[wid * 512];
  ushort_t* sB = &lB[wid * 1024];
  const int nIter = K >> 5;   // BK=32
  {
    async_copy16(sA,       gA0);
    async_copy16(sB,       gB0);
    async_copy16(sB + 512, gB0 + (size_t)16 * ldb);
  }
  if (nIter > 1) {
    async_copy16(sA + 2048,       gA0 + 32);
    async_copy16(sB + 4096,       gB0 + 32);
    async_copy16(sB + 4096 + 512, gB0 + (size_t)16 * ldb + 32);
  }
  for (int kt = 0; kt < nIter; ++kt) {
    if (kt + 1 < nIter) asm volatile("s_waitcnt vmcnt(3)" ::: "memory");
    else                asm volatile("s_waitcnt vmcnt(0)" ::: "memory");
    __builtin_amdgcn_s_barrier();
    const int curA = (kt & 1) * 2048;
    const int curB = (kt & 1) * 4096;
    bf16x8 af[2], bfr[4];
#pragma unroll
    for (int mi = 0; mi < 2; ++mi)
      af[mi] = *(const bf16x8*)&lA[curA + (wr * 32 + mi * 16 + lr) * 32 + kg * 8];
#pragma unroll
    for (int ni = 0; ni < 4; ++ni)
      bfr[ni] = *(const bf16x8*)&lB[curB + (wc * 64 + ni * 16 + lr) * 32 + kg * 8];
#pragma unroll
    for (int mi = 0; mi < 2; ++mi)
#pragma unroll
      for (int ni = 0; ni < 4; ++ni)
        acc[mi][ni] = __builtin_amdgcn_mfma_f32_16x16x32_bf16(af[mi], bfr[ni], acc[mi][ni], 0, 0, 0);
    __builtin_amdgcn_s_barrier();
    if (kt + 2 < nIter) {
      const int k2 = (kt + 2) << 5;
      async_copy16(sA + curA,       gA0 + k2);
      async_copy16(sB + curB,       gB0 + k2);
      async_copy16(sB + curB + 512, gB0 + (size_t)16 * ldb + k2);
    }
  }
  const int jj = ((n0 + wc * 64) >> 6) * 16 + lr;   // 0..511 (ni bits drop out)
#pragma unroll
  for (int mi = 0; mi < 2; ++mi) {
#pragma unroll
    for (int r = 0; r < 4; ++r) {
      const int row = m0 + wr * 32 + mi * 16 + kg * 4 + r;
      const uint2 p = *(const uint2*)&base[(size_t)row * GATEN + jj * 4];
      const float g0 = bf2f_u(p.x & 0xFFFFu) + acc[mi][0][r];
      const float g1 = bf2f_u(p.x >> 16)     + acc[mi][1][r];
      const float g2 = bf2f_u(p.y & 0xFFFFu) + acc[mi][2][r];
      const float g3 = bf2f_u(p.y >> 16)     + acc[mi][3][r];
      const float si = sigmoidf(g0);
      const float sf = sigmoidf(g1);
      const float tg = tanh_fast(g2);
      const float so = sigmoidf(g3);
      const size_t ci = (size_t)row * CDIM + jj;
      const float cn = sf * bf2f(c[ci]) + si * tg;
      if (MODE != 2) c[ci] = f2bf(cn);
      const float hr = so * tanh_fast(cn);
      if (MODE == 2) {
        out[(size_t)row * DDIM + jj] = query[(size_t)row * DDIM + jj] + hr;
      } else {
        const ushort_t hi = f2bf(hr);
        const ushort_t lo = f2bf(hr - bf2f(hi));
        A1out[(size_t)row * LDA1 + jj] = hi;
        A2out[(size_t)row * DDIM + jj] = lo;
      }
    }
  }
}

// 6-chunk split-K logits, grid (6, 32): seg=bx>>1, K-half=bx&1 (256 each),
// atomicAdd into zeroed Cf. Pure GEMM (R20 lesson: no fences/atomic-load tails).
__launch_bounds__(256)
__global__ void gemm_splitk6(const ushort_t* __restrict__ A1, const ushort_t* __restrict__ A2,
                             int lda1, int lda2,
                             const ushort_t* __restrict__ Bc, float* __restrict__ Cf) {
  TILE_COMMON()
  const int seg = blockIdx.x >> 1;       // 0..2
  const int koff = (blockIdx.x & 1) * 256;
  const int m0 = blockIdx.y * 128;
  const ushort_t* A = (seg == 1) ? A2 : A1;
  const int lda = (seg == 1) ? lda2 : lda1;
  const int ldb = 1536;
  const ushort_t* gA0 = A + (size_t)(m0 + wid * 32 + srow) * lda + koff + scol;
  const ushort_t* gB0 = Bc + (size_t)(wid * 32 + srow) * 1536 + seg * 512 + koff + scol;
  const int K = 256;
  KLOOP_DBUF()
#pragma unroll
  for (int mi = 0; mi < 4; ++mi)
#pragma unroll
    for (int ni = 0; ni < 4; ++ni)
#pragma unroll
      for (int r = 0; r < 4; ++r) {
        const int row = m0 + wr * 64 + mi * 16 + kg * 4 + r;
        const int col = wc * 64 + ni * 16 + lr;
        atomicAdd(&Cf[(size_t)row * FEWN + col], acc[mi][ni][r]);
      }
}

// Prologue mega-kernel: 1232 blocks.
//  b <  192: lgBase split-K (6x32): lgBase += Qcat-seg @ Bcat-seg^T
//  b <  208: SW (1x16): B2[:,512:640] = bf16(whhRP @ Bcat[:, :512]^T)
//  b >= 208: wide (32x32 swizzled): left=step0 gates+cell0, right=gates_base
__launch_bounds__(256)
__global__ void prologue_mega(const ushort_t* __restrict__ Qcat, const ushort_t* __restrict__ Bcat,
                              const ushort_t* __restrict__ whhRP, const ushort_t* __restrict__ wcomb,
                              float* __restrict__ lgBase, ushort_t* __restrict__ B2,
                              ushort_t* __restrict__ gbase, ushort_t* __restrict__ c,
                              ushort_t* __restrict__ A1out, ushort_t* __restrict__ A2out,
                              const float* __restrict__ b1, const float* __restrict__ b2) {
  TILE_COMMON()
  const int b = blockIdx.x;
  if (b < 192) {
    const int lbx = b % 6, lby = b / 6;
    const int seg = lbx >> 1;
    const int koff = (lbx & 1) * 256;
    const int m0 = lby * 128;
    const ushort_t* A = (seg == 1) ? Qcat + 512 : Qcat;
    const int lda = 1536, ldb = 1536;
    const ushort_t* gA0 = A + (size_t)(m0 + wid * 32 + srow) * lda + koff + scol;
    const ushort_t* gB0 = Bcat + (size_t)(wid * 32 + srow) * 1536 + seg * 512 + koff + scol;
    const int K = 256;
    KLOOP_DBUF()
#pragma unroll
    for (int mi = 0; mi < 4; ++mi)
#pragma unroll
      for (int ni = 0; ni < 4; ++ni)
#pragma unroll
        for (int r = 0; r < 4; ++r) {
          const int row = m0 + wr * 64 + mi * 16 + kg * 4 + r;
          const int col = wc * 64 + ni * 16 + lr;
          atomicAdd(&lgBase[(size_t)row * FEWN + col], acc[mi][ni][r]);
        }
  } else if (b < 208) {
    const int m0 = (b - 192) * 128;
    const int lda = 512, ldb = 1536;
    const ushort_t* gA0 = whhRP + (size_t)(m0 + wid * 32 + srow) * lda + scol;
    const ushort_t* gB0 = Bcat + (size_t)(wid * 32 + srow) * 1536 + scol;
    const int K = 512;
    KLOOP_DBUF()
#pragma unroll
    for (int mi = 0; mi < 4; ++mi)
#pragma unroll
      for (int ni = 0; ni < 4; ++ni)
#pragma unroll
        for (int r = 0; r < 4; ++r) {
          const int row = m0 + wr * 64 + mi * 16 + kg * 4 + r;
          const int col = wc * 64 + ni * 16 + lr;
          B2[(size_t)row * LDA1 + 512 + col] = f2bf(acc[mi][ni][r]);
        }
  } else {
    int bx, by;
    xcd_map(32, 32, b - 208, bx, by);
    const int m0 = by * 128, n0 = bx * 128;
    const int lda = 1536, ldb = 512;
    const ushort_t* gA0 = Qcat + (size_t)(m0 + wid * 32 + srow) * lda + scol;
    const ushort_t* gB0 = wcomb + (size_t)(n0 + wid * 32 + srow) * ldb + scol;
    const int K = 512;
    KLOOP_DBUF()
    if (n0 < 2048) {
      const int jj = ((n0 + wc * 64) >> 6) * 16 + lr;   // 0..511
      const float bi0 = b1[jj]        + b2[jj];
      const float bi2 = b1[2048 + jj] + b2[2048 + jj];
      const float bi3 = b1[3072 + jj] + b2[3072 + jj];
#pragma unroll
      for (int mi = 0; mi < 4; ++mi) {
#pragma unroll
        for (int r = 0; r < 4; ++r) {
          const int row = m0 + wr * 64 + mi * 16 + kg * 4 + r;
          const float si = sigmoidf(acc[mi][0][r] + bi0);
          const float tg = tanh_fast(acc[mi][2][r] + bi2);
          const float so = sigmoidf(acc[mi][3][r] + bi3);
          const float cn = si * tg;                      // c_prev = 0
          c[(size_t)row * CDIM + jj] = f2bf(cn);
          const float hr = so * tanh_fast(cn);
          const ushort_t hi = f2bf(hr);
          const ushort_t lo = f2bf(hr - bf2f(hi));
          A1out[(size_t)row * LDA1 + jj] = hi;
          A2out[(size_t)row * DDIM + jj] = lo;
        }
      }
    } else {
      const int jj = ((n0 - 2048 + wc * 64) >> 6) * 16 + lr;  // 0..511
      const float bi0 = b1[jj]        + b2[jj];
      const float bi1 = b1[1024 + jj] + b2[1024 + jj];
      const float bi2 = b1[2048 + jj] + b2[2048 + jj];
      const float bi3 = b1[3072 + jj] + b2[3072 + jj];
#pragma unroll
      for (int mi = 0; mi < 4; ++mi)
#pragma unroll
        for (int r = 0; r < 4; ++r) {
          const int row = m0 + wr * 64 + mi * 16 + kg * 4 + r;
          uint2 p;
          p.x = (unsigned)f2bf(acc[mi][0][r] + bi0) | ((unsigned)f2bf(acc[mi][1][r] + bi1) << 16);
          p.y = (unsigned)f2bf(acc[mi][2][r] + bi2) | ((unsigned)f2bf(acc[mi][3][r] + bi3) << 16);
          *(uint2*)&gbase[(size_t)row * GATEN + jj * 4] = p;
        }
    }
  }
}

// softmax over logits[row] + baseL[row]; attn bf16 -> A1[:, 512:640]
__global__ void softmax_kernel(const float* __restrict__ logits, const float* __restrict__ baseL,
                               ushort_t* __restrict__ A1) {
  const int row = blockIdx.x * 4 + (threadIdx.x >> 6);
  const int lane = threadIdx.x & 63;
  const size_t ro = (size_t)row * FEWN;
  const float x0 = logits[ro + lane]      + baseL[ro + lane];
  const float x1 = logits[ro + 64 + lane] + baseL[ro + 64 + lane];
  float m = fmaxf(x0, x1);
#pragma unroll
  for (int s = 32; s > 0; s >>= 1) m = fmaxf(m, __shfl_xor(m, s));
  const float e0 = __expf(x0 - m), e1 = __expf(x1 - m);
  float sum = e0 + e1;
#pragma unroll
  for (int s = 32; s > 0; s >>= 1) sum += __shfl_xor(sum, s);
  const float inv = 1.f / sum;
  A1[(size_t)row * LDA1 + 512 + lane]      = f2bf(e0 * inv);
  A1[(size_t)row * LDA1 + 512 + 64 + lane] = f2bf(e1 * inv);
}

// merged setup: wcomb | whh_both | qcat | bcat | zero-logits by blockIdx range (26880)
__global__ void setup_all(const float* __restrict__ Wih, const float* __restrict__ Whh,
                          const float* __restrict__ q, const float* __restrict__ s,
                          ushort_t* __restrict__ wcomb, ushort_t* __restrict__ B2,
                          ushort_t* __restrict__ whhRP, ushort_t* __restrict__ Q_cat,
                          ushort_t* __restrict__ B_cat, float4* __restrict__ zbase) {
  const int b = blockIdx.x;
  const int tid = threadIdx.x;
  if (b < 8192) {            // wcomb: [4096][512]
    const int idx = b * 256 + tid;
    const int r = idx >> 9, cc = idx & 511;
    ushort_t v;
    if (r < 2048) {
      v = f2bf(Wih[(size_t)orig_row(r) * 512 + cc]);
    } else {
      const int og = orig_row(r - 2048);
      v = f2bf(Wih[(size_t)og * 512 + cc] + Whh[(size_t)og * 1024 + cc]);
    }
    wcomb[idx] = v;
  } else if (b < 16384) {    // whh_both: 2048x1024
    const int idx = (b - 8192) * 256 + tid;
    const int r = idx >> 10, k = idx & 1023;
    const ushort_t v = f2bf(Whh[(size_t)orig_row(r) * 1024 + k]);
    if (k < 512) B2[(size_t)r * LDA1 + k] = v;
    else         whhRP[(size_t)r * 512 + (k - 512)] = v;
  } else if (b < 24576) {    // qcat: 4096x512
    const int idx = (b - 16384) * 256 + tid;
    const int bb = idx >> 9, cc = idx & 511;
    const float v = q[idx];
    const ushort_t hi = f2bf(v);
    const ushort_t lo = f2bf(v - bf2f(hi));
    const size_t ro = (size_t)bb * 1536;
    Q_cat[ro + cc] = hi;
    Q_cat[ro + 512 + cc] = lo;
    Q_cat[ro + 1024 + cc] = hi;
  } else if (b < 24832) {    // bcat: 128x512
    const int idx = (b - 24576) * 256 + tid;
    const int n = idx >> 9, cc = idx & 511;
    const float v = s[idx];
    const ushort_t hi = f2bf(v);
    const ushort_t lo = f2bf(v - bf2f(hi));
    const size_t ro = (size_t)n * 1536;
    B_cat[ro + cc] = hi;
    B_cat[ro + 512 + cc] = hi;
    B_cat[ro + 1024 + cc] = lo;
  } else {                   // zero logits3 + lgBase: 524288 float4s
    const int idx = (b - 24832) * 256 + tid;
    zbase[idx] = make_float4(0.f, 0.f, 0.f, 0.f);
  }
}

extern "C" void kernel_launch(void* const* d_in, const int* in_sizes, int n_in,
                              void* d_out, int out_size, void* d_ws, size_t ws_size,
                              hipStream_t stream) {
  const float* support = (const float*)d_in[0];
  const float* query   = (const float*)d_in[1];
  const float* W_ih    = (const float*)d_in[2];
  const float* W_hh    = (const float*)d_in[3];
  const float* b_ih    = (const float*)d_in[4];
  const float* b_hh    = (const float*)d_in[5];
  float* out = (float*)d_out;

  char* ws = (char*)d_ws;
  size_t off = 0;
  auto alloc = [&](size_t bytes) { char* p = ws + off; off += (bytes + 255) & ~255ull; return p; };
  ushort_t* gates_baseP = (ushort_t*)alloc((size_t)BATCH * GATEN * 2);  // 16MB
  ushort_t* cbuf        = (ushort_t*)alloc((size_t)BATCH * CDIM * 2);   // 4MB
  ushort_t* A1a         = (ushort_t*)alloc((size_t)BATCH * LDA1 * 2);   // 5MB
  ushort_t* A1b         = (ushort_t*)alloc((size_t)BATCH * LDA1 * 2);   // 5MB
  ushort_t* A2a         = (ushort_t*)alloc((size_t)BATCH * DDIM * 2);   // 4MB
  ushort_t* A2b         = (ushort_t*)alloc((size_t)BATCH * DDIM * 2);   // 4MB
  ushort_t* Q_cat       = (ushort_t*)alloc((size_t)BATCH * 1536 * 2);   // 12MB
  ushort_t* wcomb       = (ushort_t*)alloc((size_t)4096 * 512 * 2);     // 4MB
  ushort_t* B2          = (ushort_t*)alloc((size_t)GATEN * LDA1 * 2);   // 2.6MB
  ushort_t* whhRP       = (ushort_t*)alloc((size_t)GATEN * 512 * 2);    // 2MB
  ushort_t* B_cat       = (ushort_t*)alloc((size_t)FEWN * 1536 * 2);
  // zeroed-every-call region (contiguous): 3 step logit bufs + base buf
  const size_t LOFS = (size_t)BATCH * FEWN;
  float*    logits3     = (float*)   alloc(3 * LOFS * 4);               // 6MB
  float*    lgBase      = (float*)   alloc(LOFS * 4);                   // 2MB

  const dim3 blk(256);

  // setup + zero (26880 blocks)
  setup_all<<<26880, blk, 0, stream>>>(W_ih, W_hh, query, support,
                                       wcomb, B2, whhRP, Q_cat, B_cat,
                                       (float4*)logits3);

  // prologue mega: lgBase splitk (192) + SW (16) + wide (1024) co-run
  prologue_mega<<<1232, blk, 0, stream>>>(Q_cat, B_cat, whhRP, wcomb,
                                          lgBase, B2, gates_baseP, cbuf,
                                          A1a, A2a, b_ih, b_hh);

  auto attn_phase = [&](int s, ushort_t* A1, ushort_t* A2) {
    float* lg = logits3 + (size_t)s * LOFS;
    gemm_splitk6<<<dim3(6, 32), blk, 0, stream>>>(A1, A2, LDA1, DDIM, B_cat, lg);
    softmax_kernel<<<BATCH / 4, blk, 0, stream>>>(lg, lgBase, A1);
  };

  attn_phase(0, A1a, A2a);

  // step 1: A = [hr_0 | attn_0] (A1a), BM=64 grid (16,64), K=640 -> A1b/A2b
  gemm_fused64<1><<<dim3(16, 64), blk, 0, stream>>>(
      A1a, B2, gates_baseP, cbuf, A1b, A2b, nullptr, nullptr, 640, LDA1, LDA1);
  attn_phase(1, A1b, A2b);

  // step 2: A1b -> A1a/A2a
  gemm_fused64<1><<<dim3(16, 64), blk, 0, stream>>>(
      A1b, B2, gates_baseP, cbuf, A1a, A2a, nullptr, nullptr, 640, LDA1, LDA1);
  attn_phase(2, A1a, A2a);

  // step 3 (last): out = query + hr
  gemm_fused64<2><<<dim3(16, 64), blk, 0, stream>>>(
      A1a, B2, gates_baseP, cbuf, nullptr, nullptr, query, out, 640, LDA1, LDA1);
}

// Round 27
// 172.273 us; speedup vs baseline: 1.0773x; 1.0773x over previous
//
#include <hip/hip_runtime.h>

#define BATCH 4096
#define DDIM  512
#define FEWN  128
#define LDA1  640     // A1 = [hr'(512) | attn(128)]
#define GATEN 2048    // live permuted gate cols (j<512 only; j>=512 half is dead code)
#define CDIM  512     // live c-state width

typedef unsigned short ushort_t;
typedef __attribute__((ext_vector_type(8))) short bf16x8;
typedef __attribute__((ext_vector_type(4))) float f32x4;

__device__ inline ushort_t f2bf(float f) {
  unsigned u = __float_as_uint(f);
  unsigned r = (u + 0x7FFFu + ((u >> 16) & 1u)) >> 16;
  return (ushort_t)r;
}
__device__ inline float bf2f(ushort_t h) { return __uint_as_float((unsigned)h << 16); }
__device__ inline float bf2f_u(unsigned h16) { return __uint_as_float(h16 << 16); }

__device__ inline float sigmoidf(float x) { return 1.f / (1.f + __expf(-x)); }
__device__ inline float tanh_fast(float x) {
  float ax = fabsf(x);
  float t = __expf(-2.f * ax);
  float r = (1.f - t) / (1.f + t);
  return copysignf(r, x);
}

// permuted layout over LIVE cols colp<2048: j = (colp>>6)*16 + (colp&15), gate = (colp>>4)&3
__device__ inline int orig_row(int colp) {
  return ((colp >> 4) & 3) * 1024 + ((colp >> 6) << 4) + (colp & 15);
}

__device__ inline void async_copy16(ushort_t* lds, const ushort_t* g) {
  __builtin_amdgcn_global_load_lds(
      (const __attribute__((address_space(1))) unsigned int*)g,
      (__attribute__((address_space(3))) unsigned int*)lds, 16, 0, 0);
}

// XCD-aware block map (column-slice when gx%8==0, else bijective 1D)
__device__ inline void xcd_map(int gx, int gy, int id, int& bx, int& by) {
  if ((gx & 7) == 0) {
    const int cpx = gx >> 3;
    const int x = id & 7, s = id >> 3;
    bx = x * cpx + (s % cpx);
    by = s / cpx;
  } else {
    const int nwg = gx * gy;
    const int qq = nwg >> 3, rr = nwg & 7;
    const int x = id & 7, s = id >> 3;
    const int nid = (x < rr ? x * (qq + 1) : rr * (qq + 1) + (x - rr) * qq) + s;
    bx = nid % gx; by = nid / gx;
  }
}

// ---- K-loop: BK=64, double-buffered, counted vmcnt (no vmcnt(0) mid-loop).
#define STAGE8(dA, dB, kk)                                                   \
    async_copy16(dA,              gA0 + (kk));                               \
    async_copy16(dA + 512,        gA0 + (size_t)16 * lda + (kk));            \
    async_copy16(dA + 4096,       gA0 + (kk) + 32);                          \
    async_copy16(dA + 4096 + 512, gA0 + (size_t)16 * lda + (kk) + 32);       \
    async_copy16(dB,              gB0 + (kk));                               \
    async_copy16(dB + 512,        gB0 + (size_t)16 * ldb + (kk));            \
    async_copy16(dB + 4096,       gB0 + (kk) + 32);                          \
    async_copy16(dB + 4096 + 512, gB0 + (size_t)16 * ldb + (kk) + 32);

#define KLOOP_DBUF()                                                         \
  const int nIter = K >> 6;                                                  \
  { STAGE8(sA, sB, 0) }                                                      \
  if (nIter > 1) { STAGE8(sA + 8192, sB + 8192, 64) }                        \
  for (int kt = 0; kt < nIter; ++kt) {                                       \
    if (kt + 1 < nIter) asm volatile("s_waitcnt vmcnt(8)" ::: "memory");     \
    else                asm volatile("s_waitcnt vmcnt(0)" ::: "memory");     \
    __builtin_amdgcn_s_barrier();                                            \
    const int cur = (kt & 1) * 8192;                                         \
    _Pragma("unroll")                                                        \
    for (int h = 0; h < 2; ++h) {                                            \
      bf16x8 af[4], bfr[4];                                                  \
      _Pragma("unroll")                                                      \
      for (int mi = 0; mi < 4; ++mi)                                         \
        af[mi] = *(const bf16x8*)&lA[cur + h * 4096 + (wr * 64 + mi * 16 + lr) * 32 + kg * 8]; \
      _Pragma("unroll")                                                      \
      for (int ni = 0; ni < 4; ++ni)                                         \
        bfr[ni] = *(const bf16x8*)&lB[cur + h * 4096 + (wc * 64 + ni * 16 + lr) * 32 + kg * 8]; \
      _Pragma("unroll")                                                      \
      for (int mi = 0; mi < 4; ++mi)                                         \
        _Pragma("unroll")                                                    \
        for (int ni = 0; ni < 4; ++ni)                                       \
          acc[mi][ni] = __builtin_amdgcn_mfma_f32_16x16x32_bf16(af[mi], bfr[ni], acc[mi][ni], 0, 0, 0); \
    }                                                                        \
    __builtin_amdgcn_s_barrier();                                            \
    if (kt + 2 < nIter) {                                                    \
      const int k2 = (kt + 2) << 6;                                          \
      STAGE8(sA + cur, sB + cur, k2)                                         \
    }                                                                        \
  }

// common per-thread ids + LDS decl
#define TILE_COMMON()                                                        \
  __shared__ __align__(16) ushort_t lA[2 * 8192];                            \
  __shared__ __align__(16) ushort_t lB[2 * 8192];                            \
  const int tid = threadIdx.x;                                               \
  const int wid = tid >> 6, lane = tid & 63;                                 \
  const int wr = wid >> 1, wc = wid & 1;                                     \
  const int lr = lane & 15, kg = lane >> 4;                                  \
  const int srow = lane >> 2;                                                \
  const int scol = (lane & 3) * 8;                                           \
  f32x4 acc[4][4] = {};                                                      \
  ushort_t* sA = &lA[wid * 1024];                                            \
  ushort_t* sB = &lB[wid * 1024];

// Fused recurrent GEMM + LSTM cell. N=2048, K=640: A=[hr'|attn], B=[WhhL|SW].
// MODE 1: cell -> c, A1.hi, A2.lo.  MODE 2: out = query + hr. Grid (16,32).
template<int MODE>
__launch_bounds__(256)
__global__ void gemm_fused(const ushort_t* __restrict__ A, const ushort_t* __restrict__ B,
                           const ushort_t* __restrict__ base, ushort_t* __restrict__ c,
                           ushort_t* __restrict__ A1out, ushort_t* __restrict__ A2out,
                           const float* __restrict__ query, float* __restrict__ out,
                           int K, int lda, int ldb) {
  TILE_COMMON()
  int bx, by;
  xcd_map(gridDim.x, gridDim.y, blockIdx.y * gridDim.x + blockIdx.x, bx, by);
  const int m0 = by * 128, n0 = bx * 128;
  const ushort_t* gA0 = A + (size_t)(m0 + wid * 32 + srow) * lda + scol;
  const ushort_t* gB0 = B + (size_t)(n0 + wid * 32 + srow) * ldb + scol;
  KLOOP_DBUF()
  const int jj = ((n0 + wc * 64) >> 6) * 16 + lr;   // 0..511
#pragma unroll
  for (int mi = 0; mi < 4; ++mi) {
#pragma unroll
    for (int r = 0; r < 4; ++r) {
      const int row = m0 + wr * 64 + mi * 16 + kg * 4 + r;
      const uint2 p = *(const uint2*)&base[(size_t)row * GATEN + jj * 4];
      const float g0 = bf2f_u(p.x & 0xFFFFu) + acc[mi][0][r];
      const float g1 = bf2f_u(p.x >> 16)     + acc[mi][1][r];
      const float g2 = bf2f_u(p.y & 0xFFFFu) + acc[mi][2][r];
      const float g3 = bf2f_u(p.y >> 16)     + acc[mi][3][r];
      const float si = sigmoidf(g0);
      const float sf = sigmoidf(g1);
      const float tg = tanh_fast(g2);
      const float so = sigmoidf(g3);
      const size_t ci = (size_t)row * CDIM + jj;
      const float cn = sf * bf2f(c[ci]) + si * tg;
      if (MODE != 2) c[ci] = f2bf(cn);
      const float hr = so * tanh_fast(cn);
      if (MODE == 2) {
        out[(size_t)row * DDIM + jj] = query[(size_t)row * DDIM + jj] + hr;
      } else {
        const ushort_t hi = f2bf(hr);
        const ushort_t lo = f2bf(hr - bf2f(hi));
        A1out[(size_t)row * LDA1 + jj] = hi;
        A2out[(size_t)row * DDIM + jj] = lo;
      }
    }
  }
}

// 6-chunk split-K logits, grid (6, 32): seg=bx>>1, K-half=bx&1 (256 each),
// atomicAdd into zeroed Cf. Pure GEMM (R20 lesson: no fences/atomic-load tails).
__launch_bounds__(256)
__global__ void gemm_splitk6(const ushort_t* __restrict__ A1, const ushort_t* __restrict__ A2,
                             int lda1, int lda2,
                             const ushort_t* __restrict__ Bc, float* __restrict__ Cf) {
  TILE_COMMON()
  const int seg = blockIdx.x >> 1;       // 0..2
  const int koff = (blockIdx.x & 1) * 256;
  const int m0 = blockIdx.y * 128;
  const ushort_t* A = (seg == 1) ? A2 : A1;
  const int lda = (seg == 1) ? lda2 : lda1;
  const int ldb = 1536;
  const ushort_t* gA0 = A + (size_t)(m0 + wid * 32 + srow) * lda + koff + scol;
  const ushort_t* gB0 = Bc + (size_t)(wid * 32 + srow) * 1536 + seg * 512 + koff + scol;
  const int K = 256;
  KLOOP_DBUF()
#pragma unroll
  for (int mi = 0; mi < 4; ++mi)
#pragma unroll
    for (int ni = 0; ni < 4; ++ni)
#pragma unroll
      for (int r = 0; r < 4; ++r) {
        const int row = m0 + wr * 64 + mi * 16 + kg * 4 + r;
        const int col = wc * 64 + ni * 16 + lr;
        atomicAdd(&Cf[(size_t)row * FEWN + col], acc[mi][ni][r]);
      }
}

// Prologue mega-kernel: 1232 blocks.
//  b <  192: lgBase split-K (6x32): lgBase += Qcat-seg @ Bcat-seg^T
//  b <  208: SW (1x16): B2[:,512:640] = bf16(whhRP @ Bcat[:, :512]^T)
//  b >= 208: wide (32x32 swizzled): left=step0 gates+cell0, right=gates_base
__launch_bounds__(256)
__global__ void prologue_mega(const ushort_t* __restrict__ Qcat, const ushort_t* __restrict__ Bcat,
                              const ushort_t* __restrict__ whhRP, const ushort_t* __restrict__ wcomb,
                              float* __restrict__ lgBase, ushort_t* __restrict__ B2,
                              ushort_t* __restrict__ gbase, ushort_t* __restrict__ c,
                              ushort_t* __restrict__ A1out, ushort_t* __restrict__ A2out,
                              const float* __restrict__ b1, const float* __restrict__ b2) {
  TILE_COMMON()
  const int b = blockIdx.x;
  if (b < 192) {
    const int lbx = b % 6, lby = b / 6;
    const int seg = lbx >> 1;
    const int koff = (lbx & 1) * 256;
    const int m0 = lby * 128;
    const ushort_t* A = (seg == 1) ? Qcat + 512 : Qcat;
    const int lda = 1536, ldb = 1536;
    const ushort_t* gA0 = A + (size_t)(m0 + wid * 32 + srow) * lda + koff + scol;
    const ushort_t* gB0 = Bcat + (size_t)(wid * 32 + srow) * 1536 + seg * 512 + koff + scol;
    const int K = 256;
    KLOOP_DBUF()
#pragma unroll
    for (int mi = 0; mi < 4; ++mi)
#pragma unroll
      for (int ni = 0; ni < 4; ++ni)
#pragma unroll
        for (int r = 0; r < 4; ++r) {
          const int row = m0 + wr * 64 + mi * 16 + kg * 4 + r;
          const int col = wc * 64 + ni * 16 + lr;
          atomicAdd(&lgBase[(size_t)row * FEWN + col], acc[mi][ni][r]);
        }
  } else if (b < 208) {
    const int m0 = (b - 192) * 128;
    const int lda = 512, ldb = 1536;
    const ushort_t* gA0 = whhRP + (size_t)(m0 + wid * 32 + srow) * lda + scol;
    const ushort_t* gB0 = Bcat + (size_t)(wid * 32 + srow) * 1536 + scol;
    const int K = 512;
    KLOOP_DBUF()
#pragma unroll
    for (int mi = 0; mi < 4; ++mi)
#pragma unroll
      for (int ni = 0; ni < 4; ++ni)
#pragma unroll
        for (int r = 0; r < 4; ++r) {
          const int row = m0 + wr * 64 + mi * 16 + kg * 4 + r;
          const int col = wc * 64 + ni * 16 + lr;
          B2[(size_t)row * LDA1 + 512 + col] = f2bf(acc[mi][ni][r]);
        }
  } else {
    int bx, by;
    xcd_map(32, 32, b - 208, bx, by);
    const int m0 = by * 128, n0 = bx * 128;
    const int lda = 1536, ldb = 512;
    const ushort_t* gA0 = Qcat + (size_t)(m0 + wid * 32 + srow) * lda + scol;
    const ushort_t* gB0 = wcomb + (size_t)(n0 + wid * 32 + srow) * ldb + scol;
    const int K = 512;
    KLOOP_DBUF()
    if (n0 < 2048) {
      const int jj = ((n0 + wc * 64) >> 6) * 16 + lr;   // 0..511
      const float bi0 = b1[jj]        + b2[jj];
      const float bi2 = b1[2048 + jj] + b2[2048 + jj];
      const float bi3 = b1[3072 + jj] + b2[3072 + jj];
#pragma unroll
      for (int mi = 0; mi < 4; ++mi) {
#pragma unroll
        for (int r = 0; r < 4; ++r) {
          const int row = m0 + wr * 64 + mi * 16 + kg * 4 + r;
          const float si = sigmoidf(acc[mi][0][r] + bi0);
          const float tg = tanh_fast(acc[mi][2][r] + bi2);
          const float so = sigmoidf(acc[mi][3][r] + bi3);
          const float cn = si * tg;                      // c_prev = 0
          c[(size_t)row * CDIM + jj] = f2bf(cn);
          const float hr = so * tanh_fast(cn);
          const ushort_t hi = f2bf(hr);
          const ushort_t lo = f2bf(hr - bf2f(hi));
          A1out[(size_t)row * LDA1 + jj] = hi;
          A2out[(size_t)row * DDIM + jj] = lo;
        }
      }
    } else {
      const int jj = ((n0 - 2048 + wc * 64) >> 6) * 16 + lr;  // 0..511
      const float bi0 = b1[jj]        + b2[jj];
      const float bi1 = b1[1024 + jj] + b2[1024 + jj];
      const float bi2 = b1[2048 + jj] + b2[2048 + jj];
      const float bi3 = b1[3072 + jj] + b2[3072 + jj];
#pragma unroll
      for (int mi = 0; mi < 4; ++mi)
#pragma unroll
        for (int r = 0; r < 4; ++r) {
          const int row = m0 + wr * 64 + mi * 16 + kg * 4 + r;
          uint2 p;
          p.x = (unsigned)f2bf(acc[mi][0][r] + bi0) | ((unsigned)f2bf(acc[mi][1][r] + bi1) << 16);
          p.y = (unsigned)f2bf(acc[mi][2][r] + bi2) | ((unsigned)f2bf(acc[mi][3][r] + bi3) << 16);
          *(uint2*)&gbase[(size_t)row * GATEN + jj * 4] = p;
        }
    }
  }
}

// softmax over logits[row] + baseL[row]; attn bf16 -> A1[:, 512:640]
__global__ void softmax_kernel(const float* __restrict__ logits, const float* __restrict__ baseL,
                               ushort_t* __restrict__ A1) {
  const int row = blockIdx.x * 4 + (threadIdx.x >> 6);
  const int lane = threadIdx.x & 63;
  const size_t ro = (size_t)row * FEWN;
  const float x0 = logits[ro + lane]      + baseL[ro + lane];
  const float x1 = logits[ro + 64 + lane] + baseL[ro + 64 + lane];
  float m = fmaxf(x0, x1);
#pragma unroll
  for (int s = 32; s > 0; s >>= 1) m = fmaxf(m, __shfl_xor(m, s));
  const float e0 = __expf(x0 - m), e1 = __expf(x1 - m);
  float sum = e0 + e1;
#pragma unroll
  for (int s = 32; s > 0; s >>= 1) sum += __shfl_xor(sum, s);
  const float inv = 1.f / sum;
  A1[(size_t)row * LDA1 + 512 + lane]      = f2bf(e0 * inv);
  A1[(size_t)row * LDA1 + 512 + 64 + lane] = f2bf(e1 * inv);
}

// merged setup: wcomb | whh_both | qcat | bcat | zero-logits by blockIdx range (26880)
__global__ void setup_all(const float* __restrict__ Wih, const float* __restrict__ Whh,
                          const float* __restrict__ q, const float* __restrict__ s,
                          ushort_t* __restrict__ wcomb, ushort_t* __restrict__ B2,
                          ushort_t* __restrict__ whhRP, ushort_t* __restrict__ Q_cat,
                          ushort_t* __restrict__ B_cat, float4* __restrict__ zbase) {
  const int b = blockIdx.x;
  const int tid = threadIdx.x;
  if (b < 8192) {            // wcomb: [4096][512]
    const int idx = b * 256 + tid;
    const int r = idx >> 9, cc = idx & 511;
    ushort_t v;
    if (r < 2048) {
      v = f2bf(Wih[(size_t)orig_row(r) * 512 + cc]);
    } else {
      const int og = orig_row(r - 2048);
      v = f2bf(Wih[(size_t)og * 512 + cc] + Whh[(size_t)og * 1024 + cc]);
    }
    wcomb[idx] = v;
  } else if (b < 16384) {    // whh_both: 2048x1024
    const int idx = (b - 8192) * 256 + tid;
    const int r = idx >> 10, k = idx & 1023;
    const ushort_t v = f2bf(Whh[(size_t)orig_row(r) * 1024 + k]);
    if (k < 512) B2[(size_t)r * LDA1 + k] = v;
    else         whhRP[(size_t)r * 512 + (k - 512)] = v;
  } else if (b < 24576) {    // qcat: 4096x512
    const int idx = (b - 16384) * 256 + tid;
    const int bb = idx >> 9, cc = idx & 511;
    const float v = q[idx];
    const ushort_t hi = f2bf(v);
    const ushort_t lo = f2bf(v - bf2f(hi));
    const size_t ro = (size_t)bb * 1536;
    Q_cat[ro + cc] = hi;
    Q_cat[ro + 512 + cc] = lo;
    Q_cat[ro + 1024 + cc] = hi;
  } else if (b < 24832) {    // bcat: 128x512
    const int idx = (b - 24576) * 256 + tid;
    const int n = idx >> 9, cc = idx & 511;
    const float v = s[idx];
    const ushort_t hi = f2bf(v);
    const ushort_t lo = f2bf(v - bf2f(hi));
    const size_t ro = (size_t)n * 1536;
    B_cat[ro + cc] = hi;
    B_cat[ro + 512 + cc] = hi;
    B_cat[ro + 1024 + cc] = lo;
  } else {                   // zero logits3 + lgBase: 524288 float4s
    const int idx = (b - 24832) * 256 + tid;
    zbase[idx] = make_float4(0.f, 0.f, 0.f, 0.f);
  }
}

extern "C" void kernel_launch(void* const* d_in, const int* in_sizes, int n_in,
                              void* d_out, int out_size, void* d_ws, size_t ws_size,
                              hipStream_t stream) {
  const float* support = (const float*)d_in[0];
  const float* query   = (const float*)d_in[1];
  const float* W_ih    = (const float*)d_in[2];
  const float* W_hh    = (const float*)d_in[3];
  const float* b_ih    = (const float*)d_in[4];
  const float* b_hh    = (const float*)d_in[5];
  float* out = (float*)d_out;

  char* ws = (char*)d_ws;
  size_t off = 0;
  auto alloc = [&](size_t bytes) { char* p = ws + off; off += (bytes + 255) & ~255ull; return p; };
  ushort_t* gates_baseP = (ushort_t*)alloc((size_t)BATCH * GATEN * 2);  // 16MB
  ushort_t* cbuf        = (ushort_t*)alloc((size_t)BATCH * CDIM * 2);   // 4MB
  ushort_t* A1a         = (ushort_t*)alloc((size_t)BATCH * LDA1 * 2);   // 5MB
  ushort_t* A1b         = (ushort_t*)alloc((size_t)BATCH * LDA1 * 2);   // 5MB
  ushort_t* A2a         = (ushort_t*)alloc((size_t)BATCH * DDIM * 2);   // 4MB
  ushort_t* A2b         = (ushort_t*)alloc((size_t)BATCH * DDIM * 2);   // 4MB
  ushort_t* Q_cat       = (ushort_t*)alloc((size_t)BATCH * 1536 * 2);   // 12MB
  ushort_t* wcomb       = (ushort_t*)alloc((size_t)4096 * 512 * 2);     // 4MB
  ushort_t* B2          = (ushort_t*)alloc((size_t)GATEN * LDA1 * 2);   // 2.6MB
  ushort_t* whhRP       = (ushort_t*)alloc((size_t)GATEN * 512 * 2);    // 2MB
  ushort_t* B_cat       = (ushort_t*)alloc((size_t)FEWN * 1536 * 2);
  // zeroed-every-call region (contiguous): 3 step logit bufs + base buf
  const size_t LOFS = (size_t)BATCH * FEWN;
  float*    logits3     = (float*)   alloc(3 * LOFS * 4);               // 6MB
  float*    lgBase      = (float*)   alloc(LOFS * 4);                   // 2MB

  const dim3 blk(256);

  // setup + zero (26880 blocks)
  setup_all<<<26880, blk, 0, stream>>>(W_ih, W_hh, query, support,
                                       wcomb, B2, whhRP, Q_cat, B_cat,
                                       (float4*)logits3);

  // prologue mega: lgBase splitk (192) + SW (16) + wide (1024) co-run
  prologue_mega<<<1232, blk, 0, stream>>>(Q_cat, B_cat, whhRP, wcomb,
                                          lgBase, B2, gates_baseP, cbuf,
                                          A1a, A2a, b_ih, b_hh);

  auto attn_phase = [&](int s, ushort_t* A1, ushort_t* A2) {
    float* lg = logits3 + (size_t)s * LOFS;
    gemm_splitk6<<<dim3(6, 32), blk, 0, stream>>>(A1, A2, LDA1, DDIM, B_cat, lg);
    softmax_kernel<<<BATCH / 4, blk, 0, stream>>>(lg, lgBase, A1);
  };

  attn_phase(0, A1a, A2a);

  // step 1: A = [hr_0 | attn_0] (A1a), N=2048, K=640 -> A1b/A2b
  gemm_fused<1><<<dim3(16, 32), blk, 0, stream>>>(
      A1a, B2, gates_baseP, cbuf, A1b, A2b, nullptr, nullptr, 640, LDA1, LDA1);
  attn_phase(1, A1b, A2b);

  // step 2: A1b -> A1a/A2a
  gemm_fused<1><<<dim3(16, 32), blk, 0, stream>>>(
      A1b, B2, gates_baseP, cbuf, A1a, A2a, nullptr, nullptr, 640, LDA1, LDA1);
  attn_phase(2, A1a, A2a);

  // step 3 (last): out = query + hr
  gemm_fused<2><<<dim3(16, 32), blk, 0, stream>>>(
      A1a, B2, gates_baseP, cbuf, nullptr, nullptr, query, out, 640, LDA1, LDA1);
}

// Round 28
// 171.147 us; speedup vs baseline: 1.0844x; 1.0066x over previous
//
#include <hip/hip_runtime.h>

#define BATCH 4096
#define DDIM  512
#define FEWN  128
#define LDA1  640     // A1 = [hr'(512) | attn(128)]
#define GATEN 2048    // live permuted gate cols (j<512 only; j>=512 half is dead code)
#define CDIM  512     // live c-state width

typedef unsigned short ushort_t;
typedef __attribute__((ext_vector_type(8))) short bf16x8;
typedef __attribute__((ext_vector_type(4))) float f32x4;

__device__ inline ushort_t f2bf(float f) {
  unsigned u = __float_as_uint(f);
  unsigned r = (u + 0x7FFFu + ((u >> 16) & 1u)) >> 16;
  return (ushort_t)r;
}
__device__ inline float bf2f(ushort_t h) { return __uint_as_float((unsigned)h << 16); }
__device__ inline float bf2f_u(unsigned h16) { return __uint_as_float(h16 << 16); }

__device__ inline float sigmoidf(float x) { return 1.f / (1.f + __expf(-x)); }
__device__ inline float tanh_fast(float x) {
  float ax = fabsf(x);
  float t = __expf(-2.f * ax);
  float r = (1.f - t) / (1.f + t);
  return copysignf(r, x);
}

// permuted layout over LIVE cols colp<2048: j = (colp>>6)*16 + (colp&15), gate = (colp>>4)&3
__device__ inline int orig_row(int colp) {
  return ((colp >> 4) & 3) * 1024 + ((colp >> 6) << 4) + (colp & 15);
}

__device__ inline void async_copy16(ushort_t* lds, const ushort_t* g) {
  __builtin_amdgcn_global_load_lds(
      (const __attribute__((address_space(1))) unsigned int*)g,
      (__attribute__((address_space(3))) unsigned int*)lds, 16, 0, 0);
}

// XCD-aware block map (column-slice when gx%8==0, else bijective 1D)
__device__ inline void xcd_map(int gx, int gy, int id, int& bx, int& by) {
  if ((gx & 7) == 0) {
    const int cpx = gx >> 3;
    const int x = id & 7, s = id >> 3;
    bx = x * cpx + (s % cpx);
    by = s / cpx;
  } else {
    const int nwg = gx * gy;
    const int qq = nwg >> 3, rr = nwg & 7;
    const int x = id & 7, s = id >> 3;
    const int nid = (x < rr ? x * (qq + 1) : rr * (qq + 1) + (x - rr) * qq) + s;
    bx = nid % gx; by = nid / gx;
  }
}

// ---- K-loop: BK=64, double-buffered, counted vmcnt (no vmcnt(0) mid-loop).
#define STAGE8(dA, dB, kk)                                                   \
    async_copy16(dA,              gA0 + (kk));                               \
    async_copy16(dA + 512,        gA0 + (size_t)16 * lda + (kk));            \
    async_copy16(dA + 4096,       gA0 + (kk) + 32);                          \
    async_copy16(dA + 4096 + 512, gA0 + (size_t)16 * lda + (kk) + 32);       \
    async_copy16(dB,              gB0 + (kk));                               \
    async_copy16(dB + 512,        gB0 + (size_t)16 * ldb + (kk));            \
    async_copy16(dB + 4096,       gB0 + (kk) + 32);                          \
    async_copy16(dB + 4096 + 512, gB0 + (size_t)16 * ldb + (kk) + 32);

#define KLOOP_DBUF()                                                         \
  const int nIter = K >> 6;                                                  \
  { STAGE8(sA, sB, 0) }                                                      \
  if (nIter > 1) { STAGE8(sA + 8192, sB + 8192, 64) }                        \
  for (int kt = 0; kt < nIter; ++kt) {                                       \
    if (kt + 1 < nIter) asm volatile("s_waitcnt vmcnt(8)" ::: "memory");     \
    else                asm volatile("s_waitcnt vmcnt(0)" ::: "memory");     \
    __builtin_amdgcn_s_barrier();                                            \
    const int cur = (kt & 1) * 8192;                                         \
    _Pragma("unroll")                                                        \
    for (int h = 0; h < 2; ++h) {                                            \
      bf16x8 af[4], bfr[4];                                                  \
      _Pragma("unroll")                                                      \
      for (int mi = 0; mi < 4; ++mi)                                         \
        af[mi] = *(const bf16x8*)&lA[cur + h * 4096 + (wr * 64 + mi * 16 + lr) * 32 + kg * 8]; \
      _Pragma("unroll")                                                      \
      for (int ni = 0; ni < 4; ++ni)                                         \
        bfr[ni] = *(const bf16x8*)&lB[cur + h * 4096 + (wc * 64 + ni * 16 + lr) * 32 + kg * 8]; \
      _Pragma("unroll")                                                      \
      for (int mi = 0; mi < 4; ++mi)                                         \
        _Pragma("unroll")                                                    \
        for (int ni = 0; ni < 4; ++ni)                                       \
          acc[mi][ni] = __builtin_amdgcn_mfma_f32_16x16x32_bf16(af[mi], bfr[ni], acc[mi][ni], 0, 0, 0); \
    }                                                                        \
    __builtin_amdgcn_s_barrier();                                            \
    if (kt + 2 < nIter) {                                                    \
      const int k2 = (kt + 2) << 6;                                          \
      STAGE8(sA + cur, sB + cur, k2)                                         \
    }                                                                        \
  }

// common per-thread ids + LDS decl
#define TILE_COMMON()                                                        \
  __shared__ __align__(16) ushort_t lA[2 * 8192];                            \
  __shared__ __align__(16) ushort_t lB[2 * 8192];                            \
  const int tid = threadIdx.x;                                               \
  const int wid = tid >> 6, lane = tid & 63;                                 \
  const int wr = wid >> 1, wc = wid & 1;                                     \
  const int lr = lane & 15, kg = lane >> 4;                                  \
  const int srow = lane >> 2;                                                \
  const int scol = (lane & 3) * 8;                                           \
  f32x4 acc[4][4] = {};                                                      \
  ushort_t* sA = &lA[wid * 1024];                                            \
  ushort_t* sB = &lB[wid * 1024];

// Fused recurrent GEMM + LSTM cell, B SINGLE-buffered (B2 is L2-resident):
// LDS 48KB -> 3 blocks/CU (was 2). A keeps 2-deep dbuf (HBM latency), B staged
// 1 iter ahead (L2-hit latency). Same 10 barrier-pairs, identical K-order ->
// bitwise-identical numerics. vmcnt(4): newest 4 = A(kt+2) in flight.
// MODE 1: cell -> c, A1.hi, A2.lo.  MODE 2: out = query + hr. Grid (16,32).
template<int MODE>
__launch_bounds__(256)
__global__ void gemm_fused(const ushort_t* __restrict__ A, const ushort_t* __restrict__ B,
                           const ushort_t* __restrict__ base, ushort_t* __restrict__ c,
                           ushort_t* __restrict__ A1out, ushort_t* __restrict__ A2out,
                           const float* __restrict__ query, float* __restrict__ out,
                           int K, int lda, int ldb) {
  __shared__ __align__(16) ushort_t lA[2 * 8192];   // A dbuf [2][128][64]
  __shared__ __align__(16) ushort_t lB[8192];       // B single [128][64]
  const int tid = threadIdx.x;
  const int wid = tid >> 6, lane = tid & 63;
  const int wr = wid >> 1, wc = wid & 1;
  const int lr = lane & 15, kg = lane >> 4;
  const int srow = lane >> 2;
  const int scol = (lane & 3) * 8;
  f32x4 acc[4][4] = {};
  int bx, by;
  xcd_map(gridDim.x, gridDim.y, blockIdx.y * gridDim.x + blockIdx.x, bx, by);
  const int m0 = by * 128, n0 = bx * 128;
  const ushort_t* gA0 = A + (size_t)(m0 + wid * 32 + srow) * lda + scol;
  const ushort_t* gB0 = B + (size_t)(n0 + wid * 32 + srow) * ldb + scol;
  ushort_t* sA = &lA[wid * 1024];
  ushort_t* sB = &lB[wid * 1024];

#define STAGE_A(dA, kk)                                                      \
    async_copy16(dA,              gA0 + (kk));                               \
    async_copy16(dA + 512,        gA0 + (size_t)16 * lda + (kk));            \
    async_copy16(dA + 4096,       gA0 + (kk) + 32);                          \
    async_copy16(dA + 4096 + 512, gA0 + (size_t)16 * lda + (kk) + 32);
#define STAGE_B(kk)                                                          \
    async_copy16(sB,              gB0 + (kk));                               \
    async_copy16(sB + 512,        gB0 + (size_t)16 * ldb + (kk));            \
    async_copy16(sB + 4096,       gB0 + (kk) + 32);                          \
    async_copy16(sB + 4096 + 512, gB0 + (size_t)16 * ldb + (kk) + 32);

  const int nIter = K >> 6;   // 10
  { STAGE_A(sA, 0) }
  { STAGE_B(0) }
  if (nIter > 1) { STAGE_A(sA + 8192, 64) }
  for (int kt = 0; kt < nIter; ++kt) {
    if (kt + 1 < nIter) asm volatile("s_waitcnt vmcnt(4)" ::: "memory");
    else                asm volatile("s_waitcnt vmcnt(0)" ::: "memory");
    __builtin_amdgcn_s_barrier();
    const int cur = (kt & 1) * 8192;
#pragma unroll
    for (int h = 0; h < 2; ++h) {
      bf16x8 af[4], bfr[4];
#pragma unroll
      for (int mi = 0; mi < 4; ++mi)
        af[mi] = *(const bf16x8*)&lA[cur + h * 4096 + (wr * 64 + mi * 16 + lr) * 32 + kg * 8];
#pragma unroll
      for (int ni = 0; ni < 4; ++ni)
        bfr[ni] = *(const bf16x8*)&lB[h * 4096 + (wc * 64 + ni * 16 + lr) * 32 + kg * 8];
#pragma unroll
      for (int mi = 0; mi < 4; ++mi)
#pragma unroll
        for (int ni = 0; ni < 4; ++ni)
          acc[mi][ni] = __builtin_amdgcn_mfma_f32_16x16x32_bf16(af[mi], bfr[ni], acc[mi][ni], 0, 0, 0);
    }
    __builtin_amdgcn_s_barrier();
    if (kt + 1 < nIter) { const int k1 = (kt + 1) << 6; STAGE_B(k1) }
    if (kt + 2 < nIter) { const int k2 = (kt + 2) << 6; STAGE_A(sA + cur, k2) }
  }
#undef STAGE_A
#undef STAGE_B
  const int jj = ((n0 + wc * 64) >> 6) * 16 + lr;   // 0..511
#pragma unroll
  for (int mi = 0; mi < 4; ++mi) {
#pragma unroll
    for (int r = 0; r < 4; ++r) {
      const int row = m0 + wr * 64 + mi * 16 + kg * 4 + r;
      const uint2 p = *(const uint2*)&base[(size_t)row * GATEN + jj * 4];
      const float g0 = bf2f_u(p.x & 0xFFFFu) + acc[mi][0][r];
      const float g1 = bf2f_u(p.x >> 16)     + acc[mi][1][r];
      const float g2 = bf2f_u(p.y & 0xFFFFu) + acc[mi][2][r];
      const float g3 = bf2f_u(p.y >> 16)     + acc[mi][3][r];
      const float si = sigmoidf(g0);
      const float sf = sigmoidf(g1);
      const float tg = tanh_fast(g2);
      const float so = sigmoidf(g3);
      const size_t ci = (size_t)row * CDIM + jj;
      const float cn = sf * bf2f(c[ci]) + si * tg;
      if (MODE != 2) c[ci] = f2bf(cn);
      const float hr = so * tanh_fast(cn);
      if (MODE == 2) {
        out[(size_t)row * DDIM + jj] = query[(size_t)row * DDIM + jj] + hr;
      } else {
        const ushort_t hi = f2bf(hr);
        const ushort_t lo = f2bf(hr - bf2f(hi));
        A1out[(size_t)row * LDA1 + jj] = hi;
        A2out[(size_t)row * DDIM + jj] = lo;
      }
    }
  }
}

// 6-chunk split-K logits, grid (6, 32): seg=bx>>1, K-half=bx&1 (256 each),
// atomicAdd into zeroed Cf. Pure GEMM (R20 lesson: no fences/atomic-load tails).
__launch_bounds__(256)
__global__ void gemm_splitk6(const ushort_t* __restrict__ A1, const ushort_t* __restrict__ A2,
                             int lda1, int lda2,
                             const ushort_t* __restrict__ Bc, float* __restrict__ Cf) {
  TILE_COMMON()
  const int seg = blockIdx.x >> 1;       // 0..2
  const int koff = (blockIdx.x & 1) * 256;
  const int m0 = blockIdx.y * 128;
  const ushort_t* A = (seg == 1) ? A2 : A1;
  const int lda = (seg == 1) ? lda2 : lda1;
  const int ldb = 1536;
  const ushort_t* gA0 = A + (size_t)(m0 + wid * 32 + srow) * lda + koff + scol;
  const ushort_t* gB0 = Bc + (size_t)(wid * 32 + srow) * 1536 + seg * 512 + koff + scol;
  const int K = 256;
  KLOOP_DBUF()
#pragma unroll
  for (int mi = 0; mi < 4; ++mi)
#pragma unroll
    for (int ni = 0; ni < 4; ++ni)
#pragma unroll
      for (int r = 0; r < 4; ++r) {
        const int row = m0 + wr * 64 + mi * 16 + kg * 4 + r;
        const int col = wc * 64 + ni * 16 + lr;
        atomicAdd(&Cf[(size_t)row * FEWN + col], acc[mi][ni][r]);
      }
}

// Prologue mega-kernel: 1232 blocks.
//  b <  192: lgBase split-K (6x32): lgBase += Qcat-seg @ Bcat-seg^T
//  b <  208: SW (1x16): B2[:,512:640] = bf16(whhRP @ Bcat[:, :512]^T)
//  b >= 208: wide (32x32 swizzled): left=step0 gates+cell0, right=gates_base
__launch_bounds__(256)
__global__ void prologue_mega(const ushort_t* __restrict__ Qcat, const ushort_t* __restrict__ Bcat,
                              const ushort_t* __restrict__ whhRP, const ushort_t* __restrict__ wcomb,
                              float* __restrict__ lgBase, ushort_t* __restrict__ B2,
                              ushort_t* __restrict__ gbase, ushort_t* __restrict__ c,
                              ushort_t* __restrict__ A1out, ushort_t* __restrict__ A2out,
                              const float* __restrict__ b1, const float* __restrict__ b2) {
  TILE_COMMON()
  const int b = blockIdx.x;
  if (b < 192) {
    const int lbx = b % 6, lby = b / 6;
    const int seg = lbx >> 1;
    const int koff = (lbx & 1) * 256;
    const int m0 = lby * 128;
    const ushort_t* A = (seg == 1) ? Qcat + 512 : Qcat;
    const int lda = 1536, ldb = 1536;
    const ushort_t* gA0 = A + (size_t)(m0 + wid * 32 + srow) * lda + koff + scol;
    const ushort_t* gB0 = Bcat + (size_t)(wid * 32 + srow) * 1536 + seg * 512 + koff + scol;
    const int K = 256;
    KLOOP_DBUF()
#pragma unroll
    for (int mi = 0; mi < 4; ++mi)
#pragma unroll
      for (int ni = 0; ni < 4; ++ni)
#pragma unroll
        for (int r = 0; r < 4; ++r) {
          const int row = m0 + wr * 64 + mi * 16 + kg * 4 + r;
          const int col = wc * 64 + ni * 16 + lr;
          atomicAdd(&lgBase[(size_t)row * FEWN + col], acc[mi][ni][r]);
        }
  } else if (b < 208) {
    const int m0 = (b - 192) * 128;
    const int lda = 512, ldb = 1536;
    const ushort_t* gA0 = whhRP + (size_t)(m0 + wid * 32 + srow) * lda + scol;
    const ushort_t* gB0 = Bcat + (size_t)(wid * 32 + srow) * 1536 + scol;
    const int K = 512;
    KLOOP_DBUF()
#pragma unroll
    for (int mi = 0; mi < 4; ++mi)
#pragma unroll
      for (int ni = 0; ni < 4; ++ni)
#pragma unroll
        for (int r = 0; r < 4; ++r) {
          const int row = m0 + wr * 64 + mi * 16 + kg * 4 + r;
          const int col = wc * 64 + ni * 16 + lr;
          B2[(size_t)row * LDA1 + 512 + col] = f2bf(acc[mi][ni][r]);
        }
  } else {
    int bx, by;
    xcd_map(32, 32, b - 208, bx, by);
    const int m0 = by * 128, n0 = bx * 128;
    const int lda = 1536, ldb = 512;
    const ushort_t* gA0 = Qcat + (size_t)(m0 + wid * 32 + srow) * lda + scol;
    const ushort_t* gB0 = wcomb + (size_t)(n0 + wid * 32 + srow) * ldb + scol;
    const int K = 512;
    KLOOP_DBUF()
    if (n0 < 2048) {
      const int jj = ((n0 + wc * 64) >> 6) * 16 + lr;   // 0..511
      const float bi0 = b1[jj]        + b2[jj];
      const float bi2 = b1[2048 + jj] + b2[2048 + jj];
      const float bi3 = b1[3072 + jj] + b2[3072 + jj];
#pragma unroll
      for (int mi = 0; mi < 4; ++mi) {
#pragma unroll
        for (int r = 0; r < 4; ++r) {
          const int row = m0 + wr * 64 + mi * 16 + kg * 4 + r;
          const float si = sigmoidf(acc[mi][0][r] + bi0);
          const float tg = tanh_fast(acc[mi][2][r] + bi2);
          const float so = sigmoidf(acc[mi][3][r] + bi3);
          const float cn = si * tg;                      // c_prev = 0
          c[(size_t)row * CDIM + jj] = f2bf(cn);
          const float hr = so * tanh_fast(cn);
          const ushort_t hi = f2bf(hr);
          const ushort_t lo = f2bf(hr - bf2f(hi));
          A1out[(size_t)row * LDA1 + jj] = hi;
          A2out[(size_t)row * DDIM + jj] = lo;
        }
      }
    } else {
      const int jj = ((n0 - 2048 + wc * 64) >> 6) * 16 + lr;  // 0..511
      const float bi0 = b1[jj]        + b2[jj];
      const float bi1 = b1[1024 + jj] + b2[1024 + jj];
      const float bi2 = b1[2048 + jj] + b2[2048 + jj];
      const float bi3 = b1[3072 + jj] + b2[3072 + jj];
#pragma unroll
      for (int mi = 0; mi < 4; ++mi)
#pragma unroll
        for (int r = 0; r < 4; ++r) {
          const int row = m0 + wr * 64 + mi * 16 + kg * 4 + r;
          uint2 p;
          p.x = (unsigned)f2bf(acc[mi][0][r] + bi0) | ((unsigned)f2bf(acc[mi][1][r] + bi1) << 16);
          p.y = (unsigned)f2bf(acc[mi][2][r] + bi2) | ((unsigned)f2bf(acc[mi][3][r] + bi3) << 16);
          *(uint2*)&gbase[(size_t)row * GATEN + jj * 4] = p;
        }
    }
  }
}

// softmax over logits[row] + baseL[row]; attn bf16 -> A1[:, 512:640]
__global__ void softmax_kernel(const float* __restrict__ logits, const float* __restrict__ baseL,
                               ushort_t* __restrict__ A1) {
  const int row = blockIdx.x * 4 + (threadIdx.x >> 6);
  const int lane = threadIdx.x & 63;
  const size_t ro = (size_t)row * FEWN;
  const float x0 = logits[ro + lane]      + baseL[ro + lane];
  const float x1 = logits[ro + 64 + lane] + baseL[ro + 64 + lane];
  float m = fmaxf(x0, x1);
#pragma unroll
  for (int s = 32; s > 0; s >>= 1) m = fmaxf(m, __shfl_xor(m, s));
  const float e0 = __expf(x0 - m), e1 = __expf(x1 - m);
  float sum = e0 + e1;
#pragma unroll
  for (int s = 32; s > 0; s >>= 1) sum += __shfl_xor(sum, s);
  const float inv = 1.f / sum;
  A1[(size_t)row * LDA1 + 512 + lane]      = f2bf(e0 * inv);
  A1[(size_t)row * LDA1 + 512 + 64 + lane] = f2bf(e1 * inv);
}

// merged setup: wcomb | whh_both | qcat | bcat | zero-logits by blockIdx range (26880)
__global__ void setup_all(const float* __restrict__ Wih, const float* __restrict__ Whh,
                          const float* __restrict__ q, const float* __restrict__ s,
                          ushort_t* __restrict__ wcomb, ushort_t* __restrict__ B2,
                          ushort_t* __restrict__ whhRP, ushort_t* __restrict__ Q_cat,
                          ushort_t* __restrict__ B_cat, float4* __restrict__ zbase) {
  const int b = blockIdx.x;
  const int tid = threadIdx.x;
  if (b < 8192) {            // wcomb: [4096][512]
    const int idx = b * 256 + tid;
    const int r = idx >> 9, cc = idx & 511;
    ushort_t v;
    if (r < 2048) {
      v = f2bf(Wih[(size_t)orig_row(r) * 512 + cc]);
    } else {
      const int og = orig_row(r - 2048);
      v = f2bf(Wih[(size_t)og * 512 + cc] + Whh[(size_t)og * 1024 + cc]);
    }
    wcomb[idx] = v;
  } else if (b < 16384) {    // whh_both: 2048x1024
    const int idx = (b - 8192) * 256 + tid;
    const int r = idx >> 10, k = idx & 1023;
    const ushort_t v = f2bf(Whh[(size_t)orig_row(r) * 1024 + k]);
    if (k < 512) B2[(size_t)r * LDA1 + k] = v;
    else         whhRP[(size_t)r * 512 + (k - 512)] = v;
  } else if (b < 24576) {    // qcat: 4096x512
    const int idx = (b - 16384) * 256 + tid;
    const int bb = idx >> 9, cc = idx & 511;
    const float v = q[idx];
    const ushort_t hi = f2bf(v);
    const ushort_t lo = f2bf(v - bf2f(hi));
    const size_t ro = (size_t)bb * 1536;
    Q_cat[ro + cc] = hi;
    Q_cat[ro + 512 + cc] = lo;
    Q_cat[ro + 1024 + cc] = hi;
  } else if (b < 24832) {    // bcat: 128x512
    const int idx = (b - 24576) * 256 + tid;
    const int n = idx >> 9, cc = idx & 511;
    const float v = s[idx];
    const ushort_t hi = f2bf(v);
    const ushort_t lo = f2bf(v - bf2f(hi));
    const size_t ro = (size_t)n * 1536;
    B_cat[ro + cc] = hi;
    B_cat[ro + 512 + cc] = hi;
    B_cat[ro + 1024 + cc] = lo;
  } else {                   // zero logits3 + lgBase: 524288 float4s
    const int idx = (b - 24832) * 256 + tid;
    zbase[idx] = make_float4(0.f, 0.f, 0.f, 0.f);
  }
}

extern "C" void kernel_launch(void* const* d_in, const int* in_sizes, int n_in,
                              void* d_out, int out_size, void* d_ws, size_t ws_size,
                              hipStream_t stream) {
  const float* support = (const float*)d_in[0];
  const float* query   = (const float*)d_in[1];
  const float* W_ih    = (const float*)d_in[2];
  const float* W_hh    = (const float*)d_in[3];
  const float* b_ih    = (const float*)d_in[4];
  const float* b_hh    = (const float*)d_in[5];
  float* out = (float*)d_out;

  char* ws = (char*)d_ws;
  size_t off = 0;
  auto alloc = [&](size_t bytes) { char* p = ws + off; off += (bytes + 255) & ~255ull; return p; };
  ushort_t* gates_baseP = (ushort_t*)alloc((size_t)BATCH * GATEN * 2);  // 16MB
  ushort_t* cbuf        = (ushort_t*)alloc((size_t)BATCH * CDIM * 2);   // 4MB
  ushort_t* A1a         = (ushort_t*)alloc((size_t)BATCH * LDA1 * 2);   // 5MB
  ushort_t* A1b         = (ushort_t*)alloc((size_t)BATCH * LDA1 * 2);   // 5MB
  ushort_t* A2a         = (ushort_t*)alloc((size_t)BATCH * DDIM * 2);   // 4MB
  ushort_t* A2b         = (ushort_t*)alloc((size_t)BATCH * DDIM * 2);   // 4MB
  ushort_t* Q_cat       = (ushort_t*)alloc((size_t)BATCH * 1536 * 2);   // 12MB
  ushort_t* wcomb       = (ushort_t*)alloc((size_t)4096 * 512 * 2);     // 4MB
  ushort_t* B2          = (ushort_t*)alloc((size_t)GATEN * LDA1 * 2);   // 2.6MB
  ushort_t* whhRP       = (ushort_t*)alloc((size_t)GATEN * 512 * 2);    // 2MB
  ushort_t* B_cat       = (ushort_t*)alloc((size_t)FEWN * 1536 * 2);
  // zeroed-every-call region (contiguous): 3 step logit bufs + base buf
  const size_t LOFS = (size_t)BATCH * FEWN;
  float*    logits3     = (float*)   alloc(3 * LOFS * 4);               // 6MB
  float*    lgBase      = (float*)   alloc(LOFS * 4);                   // 2MB

  const dim3 blk(256);

  // setup + zero (26880 blocks)
  setup_all<<<26880, blk, 0, stream>>>(W_ih, W_hh, query, support,
                                       wcomb, B2, whhRP, Q_cat, B_cat,
                                       (float4*)logits3);

  // prologue mega: lgBase splitk (192) + SW (16) + wide (1024) co-run
  prologue_mega<<<1232, blk, 0, stream>>>(Q_cat, B_cat, whhRP, wcomb,
                                          lgBase, B2, gates_baseP, cbuf,
                                          A1a, A2a, b_ih, b_hh);

  auto attn_phase = [&](int s, ushort_t* A1, ushort_t* A2) {
    float* lg = logits3 + (size_t)s * LOFS;
    gemm_splitk6<<<dim3(6, 32), blk, 0, stream>>>(A1, A2, LDA1, DDIM, B_cat, lg);
    softmax_kernel<<<BATCH / 4, blk, 0, stream>>>(lg, lgBase, A1);
  };

  attn_phase(0, A1a, A2a);

  // step 1: A = [hr_0 | attn_0] (A1a), N=2048, K=640 -> A1b/A2b
  gemm_fused<1><<<dim3(16, 32), blk, 0, stream>>>(
      A1a, B2, gates_baseP, cbuf, A1b, A2b, nullptr, nullptr, 640, LDA1, LDA1);
  attn_phase(1, A1b, A2b);

  // step 2: A1b -> A1a/A2a
  gemm_fused<1><<<dim3(16, 32), blk, 0, stream>>>(
      A1b, B2, gates_baseP, cbuf, A1a, A2a, nullptr, nullptr, 640, LDA1, LDA1);
  attn_phase(2, A1a, A2a);

  // step 3 (last): out = query + hr
  gemm_fused<2><<<dim3(16, 32), blk, 0, stream>>>(
      A1a, B2, gates_baseP, cbuf, nullptr, nullptr, query, out, 640, LDA1, LDA1);
}